// Round 1
// baseline (244.708 us; speedup 1.0000x reference)
//
#include <hip/hip_runtime.h>

#define HW    3136      // 56*56
#define WIDTH 56
#define C     256
#define CR    64
#define NT    64
#define TT    8

static __device__ __forceinline__ float relu(float v) { return fmaxf(v, 0.0f); }

#define BN_INV 0.9999950000374997f   // 1/sqrt(1+1e-5)

// k0: transpose conv21_w [CR][C] -> wt [C][CR] so k1 reads contiguous weights
__global__ __launch_bounds__(256) void k0_transpose(const float* __restrict__ w,
                                                    float* __restrict__ wt) {
    int i = blockIdx.x * 256 + threadIdx.x;   // 0..16383
    int o = i >> 8;
    int c = i & 255;
    wt[c * CR + o] = w[o * C + c];
}

// k1: y[nt,o,p] = relu(bn21( sum_c w[o,c] * x[nt,c,p] ))
__global__ __launch_bounds__(256) void k1_conv21(const float* __restrict__ x,
                                                 const float* __restrict__ wt,
                                                 const float* __restrict__ g,
                                                 const float* __restrict__ bb,
                                                 float* __restrict__ y) {
    int gid = blockIdx.x * 256 + threadIdx.x;   // 0..200703
    int nt = gid / HW;
    int p  = gid - nt * HW;
    const float* xp = x + (size_t)nt * C * HW + p;

    float acc[CR];
#pragma unroll
    for (int o = 0; o < CR; ++o) acc[o] = 0.0f;

#pragma unroll 2
    for (int c = 0; c < C; ++c) {
        float xv = xp[(size_t)c * HW];
        const float* wc = wt + c * CR;      // uniform address -> scalar loads
#pragma unroll
        for (int o = 0; o < CR; ++o) acc[o] = fmaf(wc[o], xv, acc[o]);
    }

    float* yp = y + (size_t)nt * CR * HW + p;
#pragma unroll
    for (int o = 0; o < CR; ++o) {
        float v = fmaf(acc[o], g[o] * BN_INV, bb[o]);
        yp[(size_t)o * HW] = relu(v);
    }
}

// k2: cv[nt,k,p] = relu(bn22( (1/CR) * sum_ch y[nt,ch,p] * y[nt2,ch,p+off(k)] ))
//     nt2 = time-shifted (t -> min(t+1, T-1)) within each group of T frames
__global__ __launch_bounds__(256) void k2_corr(const float* __restrict__ y,
                                               const float* __restrict__ g,
                                               const float* __restrict__ bb,
                                               float* __restrict__ cv) {
    int gid = blockIdx.x * 256 + threadIdx.x;
    int nt = gid / HW;
    int p  = gid - nt * HW;
    int hh = p / WIDTH;
    int ww = p - hh * WIDTH;
    int t  = nt & (TT - 1);
    int nt2 = (t < TT - 1) ? nt + 1 : nt;

    const float* y1 = y + (size_t)nt  * CR * HW + p;
    const float* y2 = y + (size_t)nt2 * CR * HW + p;

    bool hv[3] = { hh > 0, true, hh < WIDTH - 1 };
    bool wv[3] = { ww > 0, true, ww < WIDTH - 1 };

    float acc[9];
#pragma unroll
    for (int k = 0; k < 9; ++k) acc[k] = 0.0f;

    for (int ch = 0; ch < CR; ++ch) {
        float a = y1[(size_t)ch * HW];
        const float* b2 = y2 + (size_t)ch * HW;
#pragma unroll
        for (int dy = 0; dy < 3; ++dy)
#pragma unroll
            for (int dx = 0; dx < 3; ++dx) {
                float v = (hv[dy] && wv[dx]) ? b2[(dy - 1) * WIDTH + (dx - 1)] : 0.0f;
                acc[dy * 3 + dx] = fmaf(a, v, acc[dy * 3 + dx]);
            }
    }

    float* cp = cv + (size_t)nt * 9 * HW + p;
    const float rcr = 1.0f / CR;
#pragma unroll
    for (int k = 0; k < 9; ++k) {
        float v = fmaf(acc[k] * rcr, g[k] * BN_INV, bb[k]);
        cp[(size_t)k * HW] = relu(v);
    }
}

// k3: out[nt,o,p] = relu( bn23( sum_k w2[o,k]*cv[nt,k,p] ) + x[nt,o,p] )
__global__ __launch_bounds__(256) void k3_conv22(const float* __restrict__ cv,
                                                 const float* __restrict__ w2,
                                                 const float* __restrict__ g,
                                                 const float* __restrict__ bb,
                                                 const float* __restrict__ x,
                                                 float* __restrict__ out) {
    int gid = blockIdx.x * 256 + threadIdx.x;
    int nt = gid / HW;
    int p  = gid - nt * HW;

    const float* cp = cv + (size_t)nt * 9 * HW + p;
    float cvv[9];
#pragma unroll
    for (int k = 0; k < 9; ++k) cvv[k] = cp[(size_t)k * HW];

    const float* xp = x   + (size_t)nt * C * HW + p;
    float*       op = out + (size_t)nt * C * HW + p;

#pragma unroll 4
    for (int o = 0; o < C; ++o) {
        float s = 0.0f;
#pragma unroll
        for (int k = 0; k < 9; ++k) s = fmaf(w2[o * 9 + k], cvv[k], s);
        float v = fmaf(s, g[o] * BN_INV, bb[o]) + xp[(size_t)o * HW];
        op[(size_t)o * HW] = relu(v);
    }
}

extern "C" void kernel_launch(void* const* d_in, const int* in_sizes, int n_in,
                              void* d_out, int out_size, void* d_ws, size_t ws_size,
                              hipStream_t stream) {
    const float* x   = (const float*)d_in[0];
    const float* w21 = (const float*)d_in[1];
    const float* g21 = (const float*)d_in[2];
    const float* b21 = (const float*)d_in[3];
    const float* g22 = (const float*)d_in[4];
    const float* b22 = (const float*)d_in[5];
    const float* w22 = (const float*)d_in[6];
    const float* g23 = (const float*)d_in[7];
    const float* b23 = (const float*)d_in[8];
    float* out = (float*)d_out;

    // y (64*64*3136 floats = 51.4MB) lives in d_out (dead before k3 overwrites it)
    float* yb  = out;
    // cv (64*9*3136 = 1,806,336 floats) + wt (16,384 floats) live in d_ws (~7.3MB)
    float* cvb = (float*)d_ws;
    float* wtb = cvb + (size_t)NT * 9 * HW;

    k0_transpose<<<64, 256, 0, stream>>>(w21, wtb);
    k1_conv21  <<<784, 256, 0, stream>>>(x, wtb, g21, b21, yb);
    k2_corr    <<<784, 256, 0, stream>>>(yb, g22, b22, cvb);
    k3_conv22  <<<784, 256, 0, stream>>>(cvb, w22, g23, b23, x, out);
}

// Round 2
// 187.902 us; speedup vs baseline: 1.3023x; 1.3023x over previous
//
#include <hip/hip_runtime.h>

#define HW    3136      // 56*56
#define WIDTH 56
#define C     256
#define CR    64
#define NT    64
#define TT    8

#define BN_INV 0.9999950000374997f   // 1/sqrt(1+1e-5)

typedef __attribute__((ext_vector_type(8))) short short8;
typedef __attribute__((ext_vector_type(4))) float f32x4;

static __device__ __forceinline__ float relu(float v) { return fmaxf(v, 0.0f); }

static __device__ __forceinline__ unsigned short f2bf(float f) {
    unsigned u = __builtin_bit_cast(unsigned, f);
    unsigned r = (u + 0x7FFFu + ((u >> 16) & 1u)) >> 16;   // RNE
    return (unsigned short)r;
}

// k0: convert conv21_w [CR][C] fp32 -> bf16 (same layout; k-contiguous for MFMA A)
__global__ __launch_bounds__(256) void k0_cvt_w(const float* __restrict__ w,
                                                unsigned short* __restrict__ wbf) {
    int i = blockIdx.x * 256 + threadIdx.x;   // 0..16383
    wbf[i] = f2bf(w[i]);
}

// k1: y[nt,o,p] = relu(bn21( sum_c w[o,c] * x[nt,c,p] ))  via MFMA bf16
// block = 4 waves, one nt x 64 pixels, all 64 outputs. grid = 64*49.
__global__ __launch_bounds__(256, 4) void k1_mfma(const float* __restrict__ x,
                                                  const unsigned short* __restrict__ wbf,
                                                  const float* __restrict__ g,
                                                  const float* __restrict__ bb,
                                                  float* __restrict__ y) {
    __shared__ unsigned short Alds[64][264];   // 64 o x (256 c + 8 pad)  = 33.0 KB
    __shared__ unsigned short Blds[64][40];    // 64 p x (32 c + 8 pad)   =  5.0 KB

    const int tid  = threadIdx.x;
    const int lane = tid & 63;
    const int wv   = tid >> 6;          // wave id 0..3
    const int blk  = blockIdx.x;
    const int nt   = blk / 49;
    const int p0   = (blk - nt * 49) * 64;

    // ---- stage A (bf16 weights) once: thread -> o = tid>>2, c-base = (tid&3)*64
    {
        const int o  = tid >> 2;
        const int cb = (tid & 3) * 64;
        const unsigned short* wp = wbf + o * C + cb;
        unsigned short* ap = &Alds[o][cb];
#pragma unroll
        for (int j = 0; j < 8; ++j)
            *(short8*)(ap + j * 8) = *(const short8*)(wp + j * 8);
    }

    // staging roles: pixel pp = lane, c-chunk = wave id
    const float* xbase = x + (size_t)nt * C * HW + p0 + lane;

    f32x4 acc[4];
#pragma unroll
    for (int mb = 0; mb < 4; ++mb) acc[mb] = (f32x4)0.0f;

    const int frow = lane & 15;         // fragment row/col index
    const int fk8  = (lane >> 4) * 8;   // fragment k offset

    for (int ks = 0; ks < 8; ++ks) {
        // issue global loads (8 coalesced dwords) before the barrier
        float xv[8];
#pragma unroll
        for (int j = 0; j < 8; ++j)
            xv[j] = xbase[(size_t)(ks * 32 + wv * 8 + j) * HW];

        __syncthreads();                // previous compute done (and A staged, ks==0)
        unsigned short* bp = &Blds[lane][wv * 8];
        union { unsigned short u[8]; short8 v; } pk;
#pragma unroll
        for (int j = 0; j < 8; ++j) pk.u[j] = f2bf(xv[j]);
        *(short8*)bp = pk.v;
        __syncthreads();                // B tile ready

        short8 bfrag = *(const short8*)&Blds[wv * 16 + frow][fk8];
#pragma unroll
        for (int mb = 0; mb < 4; ++mb) {
            short8 afrag = *(const short8*)&Alds[mb * 16 + frow][ks * 32 + fk8];
            acc[mb] = __builtin_amdgcn_mfma_f32_16x16x32_bf16(afrag, bfrag, acc[mb], 0, 0, 0);
        }
    }

    // epilogue: D col = lane&15 (pixel), row = (lane>>4)*4 + r (output o)
    const int p = p0 + wv * 16 + frow;
    float* yp = y + (size_t)nt * CR * HW + p;
    const int rbase = (lane >> 4) * 4;
#pragma unroll
    for (int mb = 0; mb < 4; ++mb) {
#pragma unroll
        for (int r = 0; r < 4; ++r) {
            int o = mb * 16 + rbase + r;
            float v = fmaf(acc[mb][r], g[o] * BN_INV, bb[o]);
            yp[(size_t)o * HW] = relu(v);
        }
    }
}

// k2: cv[nt,k,p] = relu(bn22( (1/CR) * sum_ch y[nt,ch,p] * y[nt2,ch,p+off(k)] ))
__global__ __launch_bounds__(256) void k2_corr(const float* __restrict__ y,
                                               const float* __restrict__ g,
                                               const float* __restrict__ bb,
                                               float* __restrict__ cv) {
    int gid = blockIdx.x * 256 + threadIdx.x;
    int nt = gid / HW;
    int p  = gid - nt * HW;
    int hh = p / WIDTH;
    int ww = p - hh * WIDTH;
    int t  = nt & (TT - 1);
    int nt2 = (t < TT - 1) ? nt + 1 : nt;

    const float* y1 = y + (size_t)nt  * CR * HW + p;
    const float* y2 = y + (size_t)nt2 * CR * HW + p;

    bool hv[3] = { hh > 0, true, hh < WIDTH - 1 };
    bool wv[3] = { ww > 0, true, ww < WIDTH - 1 };

    float acc[9];
#pragma unroll
    for (int k = 0; k < 9; ++k) acc[k] = 0.0f;

    for (int ch = 0; ch < CR; ++ch) {
        float a = y1[(size_t)ch * HW];
        const float* b2 = y2 + (size_t)ch * HW;
#pragma unroll
        for (int dy = 0; dy < 3; ++dy)
#pragma unroll
            for (int dx = 0; dx < 3; ++dx) {
                float v = (hv[dy] && wv[dx]) ? b2[(dy - 1) * WIDTH + (dx - 1)] : 0.0f;
                acc[dy * 3 + dx] = fmaf(a, v, acc[dy * 3 + dx]);
            }
    }

    float* cp = cv + (size_t)nt * 9 * HW + p;
    const float rcr = 1.0f / CR;
#pragma unroll
    for (int k = 0; k < 9; ++k) {
        float v = fmaf(acc[k] * rcr, g[k] * BN_INV, bb[k]);
        cp[(size_t)k * HW] = relu(v);
    }
}

// k3: out[nt,o,p] = relu( bn23( sum_k w2[o,k]*cv[nt,k,p] ) + x[nt,o,p] )
__global__ __launch_bounds__(256) void k3_conv22(const float* __restrict__ cv,
                                                 const float* __restrict__ w2,
                                                 const float* __restrict__ g,
                                                 const float* __restrict__ bb,
                                                 const float* __restrict__ x,
                                                 float* __restrict__ out) {
    int gid = blockIdx.x * 256 + threadIdx.x;
    int nt = gid / HW;
    int p  = gid - nt * HW;

    const float* cp = cv + (size_t)nt * 9 * HW + p;
    float cvv[9];
#pragma unroll
    for (int k = 0; k < 9; ++k) cvv[k] = cp[(size_t)k * HW];

    const float* xp = x   + (size_t)nt * C * HW + p;
    float*       op = out + (size_t)nt * C * HW + p;

#pragma unroll 4
    for (int o = 0; o < C; ++o) {
        float s = 0.0f;
#pragma unroll
        for (int k = 0; k < 9; ++k) s = fmaf(w2[o * 9 + k], cvv[k], s);
        float v = fmaf(s, g[o] * BN_INV, bb[o]) + xp[(size_t)o * HW];
        op[(size_t)o * HW] = relu(v);
    }
}

extern "C" void kernel_launch(void* const* d_in, const int* in_sizes, int n_in,
                              void* d_out, int out_size, void* d_ws, size_t ws_size,
                              hipStream_t stream) {
    const float* x   = (const float*)d_in[0];
    const float* w21 = (const float*)d_in[1];
    const float* g21 = (const float*)d_in[2];
    const float* b21 = (const float*)d_in[3];
    const float* g22 = (const float*)d_in[4];
    const float* b22 = (const float*)d_in[5];
    const float* w22 = (const float*)d_in[6];
    const float* g23 = (const float*)d_in[7];
    const float* b23 = (const float*)d_in[8];
    float* out = (float*)d_out;

    // y (64*64*3136 fp32 = 51.4MB) lives in d_out (dead before k3 overwrites it)
    float* yb  = out;
    // cv (64*9*3136 fp32 = 7.2MB) + wbf (16384 bf16 = 32KB) live in d_ws
    float* cvb = (float*)d_ws;
    unsigned short* wbf = (unsigned short*)(cvb + (size_t)NT * 9 * HW);

    k0_cvt_w <<<64,   256, 0, stream>>>(w21, wbf);
    k1_mfma  <<<3136, 256, 0, stream>>>(x, wbf, g21, b21, yb);
    k2_corr  <<<784,  256, 0, stream>>>(yb, g22, b22, cvb);
    k3_conv22<<<784,  256, 0, stream>>>(cvb, w22, g23, b23, x, out);
}